// Round 1
// baseline (734.363 us; speedup 1.0000x reference)
//
#include <hip/hip_runtime.h>

#define H 256
#define LSEQ 200
#define NB 16
#define BL 3200           // NB * LSEQ
#define V1 50001
#define NPAD 50048        // V1 padded up to multiple of 64

typedef __attribute__((ext_vector_type(8))) short short8;
typedef __attribute__((ext_vector_type(4))) float f32x4;

__device__ __forceinline__ unsigned short f2bf(float f) {
    unsigned int u = __builtin_bit_cast(unsigned int, f);
    u += 0x7fffu + ((u >> 16) & 1u);   // round-to-nearest-even
    return (unsigned short)(u >> 16);
}

// ---------------- weight prep ----------------

__global__ void k_f32_to_bf16(const float* __restrict__ src,
                              unsigned short* __restrict__ dst, int n) {
    int i = blockIdx.x * blockDim.x + threadIdx.x;
    if (i < n) dst[i] = f2bf(src[i]);
}

// Wc[i] = Wo[i] @ Wv[i]  (o,h) = sum_m Wo[o,m]*Wv[m,h]; write bf16
__global__ void k_wc(const float* __restrict__ Wo, const float* __restrict__ Wv,
                     unsigned short* __restrict__ Wc) {
    int i = blockIdx.y;       // layer block
    int o = blockIdx.x;       // out row
    int h = threadIdx.x;      // col
    const float* wo = Wo + ((size_t)i * H + o) * H;
    const float* wv = Wv + (size_t)i * H * H + h;
    float acc = 0.0f;
#pragma unroll 8
    for (int m = 0; m < H; ++m) acc = fmaf(wo[m], wv[(size_t)m * H], acc);
    Wc[((size_t)i * H + o) * H + h] = f2bf(acc);
}

// item_emb f32 (V1 x H) -> bf16 (NPAD x H), pad rows zeroed. 4 elems/thread.
__global__ void k_conv_emb(const float* __restrict__ src, unsigned short* __restrict__ dst) {
    size_t i4 = (size_t)blockIdx.x * blockDim.x + threadIdx.x;
    size_t total4 = (size_t)NPAD * H / 4;
    if (i4 >= total4) return;
    size_t e0 = i4 * 4;
    size_t row = e0 >> 8;
    ushort4 o;
    if (row < V1) {
        float4 v = *(const float4*)(src + e0);
        o.x = f2bf(v.x); o.y = f2bf(v.y); o.z = f2bf(v.z); o.w = f2bf(v.w);
    } else {
        o.x = o.y = o.z = o.w = 0;
    }
    *(ushort4*)(dst + e0) = o;
}

// ---------------- LayerNorm kernels ----------------

__device__ __forceinline__ void block_reduce2(float& s, float& ss, float* red) {
#pragma unroll
    for (int off = 32; off > 0; off >>= 1) {
        s += __shfl_down(s, off);
        ss += __shfl_down(ss, off);
    }
    int t = threadIdx.x;
    if ((t & 63) == 0) { red[(t >> 6) * 2] = s; red[(t >> 6) * 2 + 1] = ss; }
    __syncthreads();
    s  = red[0] + red[2] + red[4] + red[6];
    ss = red[1] + red[3] + red[5] + red[7];
}

__global__ __launch_bounds__(256) void k_embed_ln(
    const int* __restrict__ ids, const float* __restrict__ emb,
    const float* __restrict__ pos, const float* __restrict__ g,
    const float* __restrict__ bta, float* __restrict__ xf,
    unsigned short* __restrict__ xb) {
    __shared__ float red[8];
    int bl = blockIdx.x;
    int h = threadIdx.x;
    int l = bl % LSEQ;
    int id = ids[bl];
    float val = emb[(size_t)id * H + h] * 16.0f + pos[(size_t)l * H + h];
    float s = val, ss = val * val;
    block_reduce2(s, ss, red);
    float mean = s * (1.0f / H);
    float var = fmaxf(ss * (1.0f / H) - mean * mean, 0.0f);
    float rs = rsqrtf(var + 1e-8f);
    float keep = (id != 0) ? 1.0f : 0.0f;
    float o = ((val - mean) * rs * g[h] + bta[h]) * keep;
    xf[(size_t)bl * H + h] = o;
    xb[(size_t)bl * H + h] = f2bf(o);
}

__global__ __launch_bounds__(256) void k_add_ln(
    const float* __restrict__ x, const float* __restrict__ d,
    const float* __restrict__ g, const float* __restrict__ bta,
    const int* __restrict__ ids, float* __restrict__ xf,
    unsigned short* __restrict__ xb) {
    __shared__ float red[8];
    int bl = blockIdx.x;
    int h = threadIdx.x;
    float val = x[(size_t)bl * H + h] + d[(size_t)bl * H + h];
    float s = val, ss = val * val;
    block_reduce2(s, ss, red);
    float mean = s * (1.0f / H);
    float var = fmaxf(ss * (1.0f / H) - mean * mean, 0.0f);
    float rs = rsqrtf(var + 1e-8f);
    float keep = (ids[bl] != 0) ? 1.0f : 0.0f;
    float o = ((val - mean) * rs * g[h] + bta[h]) * keep;
    xf[(size_t)bl * H + h] = o;
    xb[(size_t)bl * H + h] = f2bf(o);
}

// causal mean: in-place v[b,l,h] = (sum_{l'<=l} v[b,l',h]) / (l+1)
__global__ void k_cumsum(float* __restrict__ v) {
    int b = blockIdx.x, h = threadIdx.x;
    float* p = v + (size_t)b * LSEQ * H + h;
    float acc = 0.0f;
    for (int l = 0; l < LSEQ; ++l) {
        acc += p[(size_t)l * H];
        p[(size_t)l * H] = acc * (1.0f / (float)(l + 1));
    }
}

// ---------------- MFMA GEMM: out[m,n] = sum_k A[m,k]*B[n,k] ----------------
// A: M x K bf16 (M = gridDim.x*64), B: Npad x K bf16, out row-major ldc=N.
template<int BIAS, int RELU, int WF32, int WBF16, int NMASK>
__global__ __launch_bounds__(256) void k_gemm64(
    const unsigned short* __restrict__ A,
    const unsigned short* __restrict__ Bmat,
    const float* __restrict__ bias,
    float* __restrict__ outF,
    unsigned short* __restrict__ outB,
    int N, int K) {
    int bm = blockIdx.x * 64;
    int bn = blockIdx.y * 64;
    int tid = threadIdx.x;
    int w = tid >> 6, l = tid & 63;
    int wr = (w >> 1) * 32, wc = (w & 1) * 32;
    int l16 = l & 15, lk = (l >> 4) * 8;

    const unsigned short* Ap = A + (size_t)(bm + wr + l16) * K + lk;
    const unsigned short* Bp = Bmat + (size_t)(bn + wc + l16) * K + lk;

    f32x4 acc00 = {0.f,0.f,0.f,0.f}, acc01 = {0.f,0.f,0.f,0.f};
    f32x4 acc10 = {0.f,0.f,0.f,0.f}, acc11 = {0.f,0.f,0.f,0.f};

#pragma unroll
    for (int k0 = 0; k0 < 256; k0 += 32) {
        short8 a0 = *(const short8*)(Ap + k0);
        short8 a1 = *(const short8*)(Ap + (size_t)16 * K + k0);
        short8 b0 = *(const short8*)(Bp + k0);
        short8 b1 = *(const short8*)(Bp + (size_t)16 * K + k0);
        acc00 = __builtin_amdgcn_mfma_f32_16x16x32_bf16(a0, b0, acc00, 0, 0, 0);
        acc01 = __builtin_amdgcn_mfma_f32_16x16x32_bf16(a0, b1, acc01, 0, 0, 0);
        acc10 = __builtin_amdgcn_mfma_f32_16x16x32_bf16(a1, b0, acc10, 0, 0, 0);
        acc11 = __builtin_amdgcn_mfma_f32_16x16x32_bf16(a1, b1, acc11, 0, 0, 0);
    }

    int r0 = (l >> 4) * 4;
#pragma unroll
    for (int i = 0; i < 2; ++i) {
#pragma unroll
        for (int j = 0; j < 2; ++j) {
            f32x4 a = (i == 0) ? (j == 0 ? acc00 : acc01) : (j == 0 ? acc10 : acc11);
            int col = bn + wc + j * 16 + l16;
            if (NMASK && col >= N) continue;
            float bv = BIAS ? bias[col] : 0.0f;
            int rowb = bm + wr + i * 16 + r0;
#pragma unroll
            for (int r = 0; r < 4; ++r) {
                float vv = a[r] + bv;
                if (RELU) vv = fmaxf(vv, 0.0f);
                size_t idx = (size_t)(rowb + r) * N + col;
                if (WF32) outF[idx] = vv;
                if (WBF16) outB[idx] = f2bf(vv);
            }
        }
    }
}

// ---------------- driver ----------------

extern "C" void kernel_launch(void* const* d_in, const int* in_sizes, int n_in,
                              void* d_out, int out_size, void* d_ws, size_t ws_size,
                              hipStream_t stream) {
    const int*   ids      = (const int*)d_in[0];
    const float* item_emb = (const float*)d_in[1];
    const float* pos_emb  = (const float*)d_in[2];
    const float* emb_g    = (const float*)d_in[3];
    const float* emb_b    = (const float*)d_in[4];
    const float* Wv       = (const float*)d_in[5];
    const float* Wo       = (const float*)d_in[6];
    const float* attn_g   = (const float*)d_in[7];
    const float* attn_b   = (const float*)d_in[8];
    const float* W1       = (const float*)d_in[9];
    const float* b1       = (const float*)d_in[10];
    const float* W2       = (const float*)d_in[11];
    const float* b2       = (const float*)d_in[12];
    const float* ffn_g    = (const float*)d_in[13];
    const float* ffn_b    = (const float*)d_in[14];
    float* out = (float*)d_out;

    char* ws = (char*)d_ws;
    size_t off = 0;
    auto alloc = [&](size_t bytes) -> void* {
        void* p = ws + off;
        off += (bytes + 255) & ~(size_t)255;
        return p;
    };
    float* xf  = (float*)alloc((size_t)BL * H * 4);
    float* vbuf= (float*)alloc((size_t)BL * H * 4);
    float* y2  = (float*)alloc((size_t)BL * H * 4);
    unsigned short* xb  = (unsigned short*)alloc((size_t)BL * H * 2);
    unsigned short* y1b = (unsigned short*)alloc((size_t)BL * H * 2);
    unsigned short* WcB = (unsigned short*)alloc((size_t)2 * H * H * 2);
    unsigned short* W1B = (unsigned short*)alloc((size_t)2 * H * H * 2);
    unsigned short* W2B = (unsigned short*)alloc((size_t)2 * H * H * 2);
    unsigned short* embB= (unsigned short*)alloc((size_t)NPAD * H * 2);

    // --- prep ---
    k_f32_to_bf16<<<dim3(512), dim3(256), 0, stream>>>(W1, W1B, 2 * H * H);
    k_f32_to_bf16<<<dim3(512), dim3(256), 0, stream>>>(W2, W2B, 2 * H * H);
    k_wc<<<dim3(H, 2), dim3(H), 0, stream>>>(Wo, Wv, WcB);
    {
        int n4 = NPAD * H / 4;
        k_conv_emb<<<dim3((n4 + 255) / 256), dim3(256), 0, stream>>>(item_emb, embB);
    }

    // --- embedding + LN ---
    k_embed_ln<<<dim3(BL), dim3(H), 0, stream>>>(ids, item_emb, pos_emb, emb_g, emb_b, xf, xb);

    // --- transformer blocks ---
    for (int i = 0; i < 2; ++i) {
        // v = x @ Wc^T
        k_gemm64<0,0,1,0,0><<<dim3(BL / 64, H / 64), dim3(256), 0, stream>>>(
            xb, WcB + (size_t)i * H * H, nullptr, vbuf, nullptr, H, H);
        // mixed = cumsum(v)/counts (in place)
        k_cumsum<<<dim3(NB), dim3(H), 0, stream>>>(vbuf);
        // x = LN(x + mixed)*keep
        k_add_ln<<<dim3(BL), dim3(H), 0, stream>>>(
            xf, vbuf, attn_g + (size_t)i * H, attn_b + (size_t)i * H, ids, xf, xb);
        // y1 = relu(x @ W1^T + b1)  (bf16 only)
        k_gemm64<1,1,0,1,0><<<dim3(BL / 64, H / 64), dim3(256), 0, stream>>>(
            xb, W1B + (size_t)i * H * H, b1 + (size_t)i * H, nullptr, y1b, H, H);
        // y2 = y1 @ W2^T + b2
        k_gemm64<1,0,1,0,0><<<dim3(BL / 64, H / 64), dim3(256), 0, stream>>>(
            y1b, W2B + (size_t)i * H * H, b2 + (size_t)i * H, y2, nullptr, H, H);
        // x = LN(x + y2)*keep
        k_add_ln<<<dim3(BL), dim3(H), 0, stream>>>(
            xf, y2, ffn_g + (size_t)i * H, ffn_b + (size_t)i * H, ids, xf, xb);
    }

    // --- logits = x @ item_emb^T ---
    k_gemm64<0,0,1,0,1><<<dim3(BL / 64, NPAD / 64), dim3(256), 0, stream>>>(
        xb, embB, nullptr, out, nullptr, V1, H);
}

// Round 2
// 423.409 us; speedup vs baseline: 1.7344x; 1.7344x over previous
//
#include <hip/hip_runtime.h>

#define H 256
#define LSEQ 200
#define NB 16
#define BL 3200           // NB * LSEQ
#define V1 50001
#define NPAD 50048        // V1 padded up to multiple of 64

#define GAS __attribute__((address_space(1)))
#define LAS __attribute__((address_space(3)))

typedef __attribute__((ext_vector_type(8))) short short8;
typedef __attribute__((ext_vector_type(4))) float f32x4;

__device__ __forceinline__ unsigned short f2bf(float f) {
    unsigned int u = __builtin_bit_cast(unsigned int, f);
    u += 0x7fffu + ((u >> 16) & 1u);   // round-to-nearest-even
    return (unsigned short)(u >> 16);
}

// ---------------- weight prep ----------------

__global__ void k_f32_to_bf16(const float* __restrict__ src,
                              unsigned short* __restrict__ dst, int n) {
    int i = blockIdx.x * blockDim.x + threadIdx.x;
    if (i < n) dst[i] = f2bf(src[i]);
}

// Wc[i] = Wo[i] @ Wv[i]  (o,h) = sum_m Wo[o,m]*Wv[m,h]; write bf16
__global__ void k_wc(const float* __restrict__ Wo, const float* __restrict__ Wv,
                     unsigned short* __restrict__ Wc) {
    int i = blockIdx.y;       // layer block
    int o = blockIdx.x;       // out row
    int h = threadIdx.x;      // col
    const float* wo = Wo + ((size_t)i * H + o) * H;
    const float* wv = Wv + (size_t)i * H * H + h;
    float acc = 0.0f;
#pragma unroll 8
    for (int m = 0; m < H; ++m) acc = fmaf(wo[m], wv[(size_t)m * H], acc);
    Wc[((size_t)i * H + o) * H + h] = f2bf(acc);
}

// item_emb f32 (V1 x H) -> bf16 (NPAD x H), pad rows zeroed. 4 elems/thread.
__global__ void k_conv_emb(const float* __restrict__ src, unsigned short* __restrict__ dst) {
    size_t i4 = (size_t)blockIdx.x * blockDim.x + threadIdx.x;
    size_t total4 = (size_t)NPAD * H / 4;
    if (i4 >= total4) return;
    size_t e0 = i4 * 4;
    size_t row = e0 >> 8;
    ushort4 o;
    if (row < V1) {
        float4 v = *(const float4*)(src + e0);
        o.x = f2bf(v.x); o.y = f2bf(v.y); o.z = f2bf(v.z); o.w = f2bf(v.w);
    } else {
        o.x = o.y = o.z = o.w = 0;
    }
    *(ushort4*)(dst + e0) = o;
}

// ---------------- LayerNorm kernels ----------------

__device__ __forceinline__ void block_reduce2(float& s, float& ss, float* red) {
#pragma unroll
    for (int off = 32; off > 0; off >>= 1) {
        s += __shfl_down(s, off);
        ss += __shfl_down(ss, off);
    }
    int t = threadIdx.x;
    if ((t & 63) == 0) { red[(t >> 6) * 2] = s; red[(t >> 6) * 2 + 1] = ss; }
    __syncthreads();
    s  = red[0] + red[2] + red[4] + red[6];
    ss = red[1] + red[3] + red[5] + red[7];
}

__global__ __launch_bounds__(256) void k_embed_ln(
    const int* __restrict__ ids, const float* __restrict__ emb,
    const float* __restrict__ pos, const float* __restrict__ g,
    const float* __restrict__ bta, float* __restrict__ xf,
    unsigned short* __restrict__ xb) {
    __shared__ float red[8];
    int bl = blockIdx.x;
    int h = threadIdx.x;
    int l = bl % LSEQ;
    int id = ids[bl];
    float val = emb[(size_t)id * H + h] * 16.0f + pos[(size_t)l * H + h];
    float s = val, ss = val * val;
    block_reduce2(s, ss, red);
    float mean = s * (1.0f / H);
    float var = fmaxf(ss * (1.0f / H) - mean * mean, 0.0f);
    float rs = rsqrtf(var + 1e-8f);
    float keep = (id != 0) ? 1.0f : 0.0f;
    float o = ((val - mean) * rs * g[h] + bta[h]) * keep;
    xf[(size_t)bl * H + h] = o;
    xb[(size_t)bl * H + h] = f2bf(o);
}

__global__ __launch_bounds__(256) void k_add_ln(
    const float* __restrict__ x, const float* __restrict__ d,
    const float* __restrict__ g, const float* __restrict__ bta,
    const int* __restrict__ ids, float* __restrict__ xf,
    unsigned short* __restrict__ xb) {
    __shared__ float red[8];
    int bl = blockIdx.x;
    int h = threadIdx.x;
    float val = x[(size_t)bl * H + h] + d[(size_t)bl * H + h];
    float s = val, ss = val * val;
    block_reduce2(s, ss, red);
    float mean = s * (1.0f / H);
    float var = fmaxf(ss * (1.0f / H) - mean * mean, 0.0f);
    float rs = rsqrtf(var + 1e-8f);
    float keep = (ids[bl] != 0) ? 1.0f : 0.0f;
    float o = ((val - mean) * rs * g[h] + bta[h]) * keep;
    xf[(size_t)bl * H + h] = o;
    xb[(size_t)bl * H + h] = f2bf(o);
}

// causal mean: in-place v[b,l,h] = (sum_{l'<=l} v[b,l',h]) / (l+1)
__global__ void k_cumsum(float* __restrict__ v) {
    int b = blockIdx.x, h = threadIdx.x;
    float* p = v + (size_t)b * LSEQ * H + h;
    float acc = 0.0f;
    for (int l = 0; l < LSEQ; ++l) {
        acc += p[(size_t)l * H];
        p[(size_t)l * H] = acc * (1.0f / (float)(l + 1));
    }
}

// ---------------- small MFMA GEMM (H x H weights) ----------------
// out[m,n] = sum_k A[m,k]*B[n,k]
template<int BIAS, int RELU, int WF32, int WBF16>
__global__ __launch_bounds__(256) void k_gemm64(
    const unsigned short* __restrict__ A,
    const unsigned short* __restrict__ Bmat,
    const float* __restrict__ bias,
    float* __restrict__ outF,
    unsigned short* __restrict__ outB,
    int N, int K) {
    int bm = blockIdx.x * 64;
    int bn = blockIdx.y * 64;
    int tid = threadIdx.x;
    int w = tid >> 6, l = tid & 63;
    int wr = (w >> 1) * 32, wc = (w & 1) * 32;
    int l16 = l & 15, lk = (l >> 4) * 8;

    const unsigned short* Ap = A + (size_t)(bm + wr + l16) * K + lk;
    const unsigned short* Bp = Bmat + (size_t)(bn + wc + l16) * K + lk;

    f32x4 acc00 = {0.f,0.f,0.f,0.f}, acc01 = {0.f,0.f,0.f,0.f};
    f32x4 acc10 = {0.f,0.f,0.f,0.f}, acc11 = {0.f,0.f,0.f,0.f};

#pragma unroll
    for (int k0 = 0; k0 < 256; k0 += 32) {
        short8 a0 = *(const short8*)(Ap + k0);
        short8 a1 = *(const short8*)(Ap + (size_t)16 * K + k0);
        short8 b0 = *(const short8*)(Bp + k0);
        short8 b1 = *(const short8*)(Bp + (size_t)16 * K + k0);
        acc00 = __builtin_amdgcn_mfma_f32_16x16x32_bf16(a0, b0, acc00, 0, 0, 0);
        acc01 = __builtin_amdgcn_mfma_f32_16x16x32_bf16(a0, b1, acc01, 0, 0, 0);
        acc10 = __builtin_amdgcn_mfma_f32_16x16x32_bf16(a1, b0, acc10, 0, 0, 0);
        acc11 = __builtin_amdgcn_mfma_f32_16x16x32_bf16(a1, b1, acc11, 0, 0, 0);
    }

    int r0 = (l >> 4) * 4;
#pragma unroll
    for (int i = 0; i < 2; ++i) {
#pragma unroll
        for (int j = 0; j < 2; ++j) {
            f32x4 a = (i == 0) ? (j == 0 ? acc00 : acc01) : (j == 0 ? acc10 : acc11);
            int col = bn + wc + j * 16 + l16;
            float bv = BIAS ? bias[col] : 0.0f;
            int rowb = bm + wr + i * 16 + r0;
#pragma unroll
            for (int r = 0; r < 4; ++r) {
                float vv = a[r] + bv;
                if (RELU) vv = fmaxf(vv, 0.0f);
                size_t idx = (size_t)(rowb + r) * N + col;
                if (WF32) outF[idx] = vv;
                if (WBF16) outB[idx] = f2bf(vv);
            }
        }
    }
}

// ---------------- logits GEMM: out[m,n] = sum_k A[m,k]*B[n,k] ----------------
// M=3200 (25 blocks of 128), Npad=50048 (391 blocks of 128), K=256.
// m97 structure: 128x128 tile, BK=32, dbuf LDS via global_load_lds(16B),
// chunk-XOR swizzle (c ^= row&3) applied on the GLOBAL source (linear LDS dest)
// and again on the ds_read address. Bijective XCD swizzle, M-fast.
#define LGM 25
#define LGN 391
#define LGWG (LGM * LGN)   // 9775

__global__ __launch_bounds__(256, 3) void k_logits(
    const unsigned short* __restrict__ A,   // BL x 256 bf16
    const unsigned short* __restrict__ B,   // NPAD x 256 bf16
    float* __restrict__ out) {              // BL x V1 f32
    __shared__ unsigned short lA[2][128 * 32];
    __shared__ unsigned short lB[2][128 * 32];

    // bijective XCD swizzle over 9775 workgroups (9775 = 8*1221 + 7)
    int orig = blockIdx.x;
    int q = LGWG >> 3, r = LGWG & 7;
    int xcd = orig & 7, sub = orig >> 3;
    int wg = (xcd < r ? xcd * (q + 1) : r * (q + 1) + (xcd - r) * q) + sub;
    int mi = wg % LGM, ni = wg / LGM;      // M fast -> consecutive wgs share B tile
    int bm = mi * 128, bn = ni * 128;

    int tid = threadIdx.x;
    int w = tid >> 6, l = tid & 63;
    int wr = (w >> 1) * 64, wc = (w & 1) * 64;
    int l16 = l & 15, lc = l >> 4;

    f32x4 acc[4][4] = {};

    auto stage = [&](int buf, int kt) {
        int k0 = kt * 32;
#pragma unroll
        for (int rr = 0; rr < 2; ++rr) {
            int t = tid + rr * 256;
            int row = t >> 2;              // 0..127
            int cd = t & 3;                // dest 16B chunk within row
            int cs = cd ^ (row & 3);       // swizzled source chunk
            unsigned short* lpA = &lA[buf][(t & ~63) * 8];   // wave-uniform
            unsigned short* lpB = &lB[buf][(t & ~63) * 8];
            const unsigned short* gA = A + (size_t)(bm + row) * 256 + k0 + cs * 8;
            const unsigned short* gB = B + (size_t)(bn + row) * 256 + k0 + cs * 8;
            __builtin_amdgcn_global_load_lds((const GAS unsigned int*)gA,
                                             (LAS unsigned int*)lpA, 16, 0, 0);
            __builtin_amdgcn_global_load_lds((const GAS unsigned int*)gB,
                                             (LAS unsigned int*)lpB, 16, 0, 0);
        }
    };

    int buf = 0;
    stage(0, 0);
    __syncthreads();

#pragma unroll
    for (int kt = 0; kt < 8; ++kt) {
        if (kt < 7) stage(buf ^ 1, kt + 1);
        short8 af[4], bf[4];
#pragma unroll
        for (int i = 0; i < 4; ++i) {
            int rowA = wr + i * 16 + l16;
            af[i] = *(const short8*)&lA[buf][rowA * 32 + ((lc ^ (rowA & 3)) * 8)];
            int rowB = wc + i * 16 + l16;
            bf[i] = *(const short8*)&lB[buf][rowB * 32 + ((lc ^ (rowB & 3)) * 8)];
        }
#pragma unroll
        for (int i = 0; i < 4; ++i)
#pragma unroll
            for (int j = 0; j < 4; ++j)
                acc[i][j] = __builtin_amdgcn_mfma_f32_16x16x32_bf16(
                    af[i], bf[j], acc[i][j], 0, 0, 0);
        __syncthreads();
        buf ^= 1;
    }

    // epilogue: col dim (lane&15) = B rows = N (contiguous across lanes)
#pragma unroll
    for (int i = 0; i < 4; ++i) {
        int mrow = bm + wr + i * 16 + lc * 4;
#pragma unroll
        for (int j = 0; j < 4; ++j) {
            int n = bn + wc + j * 16 + l16;
            if (n < V1) {
#pragma unroll
                for (int rg = 0; rg < 4; ++rg)
                    out[(size_t)(mrow + rg) * V1 + n] = acc[i][j][rg];
            }
        }
    }
}

// ---------------- driver ----------------

extern "C" void kernel_launch(void* const* d_in, const int* in_sizes, int n_in,
                              void* d_out, int out_size, void* d_ws, size_t ws_size,
                              hipStream_t stream) {
    const int*   ids      = (const int*)d_in[0];
    const float* item_emb = (const float*)d_in[1];
    const float* pos_emb  = (const float*)d_in[2];
    const float* emb_g    = (const float*)d_in[3];
    const float* emb_b    = (const float*)d_in[4];
    const float* Wv       = (const float*)d_in[5];
    const float* Wo       = (const float*)d_in[6];
    const float* attn_g   = (const float*)d_in[7];
    const float* attn_b   = (const float*)d_in[8];
    const float* W1       = (const float*)d_in[9];
    const float* b1       = (const float*)d_in[10];
    const float* W2       = (const float*)d_in[11];
    const float* b2       = (const float*)d_in[12];
    const float* ffn_g    = (const float*)d_in[13];
    const float* ffn_b    = (const float*)d_in[14];
    float* out = (float*)d_out;

    char* ws = (char*)d_ws;
    size_t off = 0;
    auto alloc = [&](size_t bytes) -> void* {
        void* p = ws + off;
        off += (bytes + 255) & ~(size_t)255;
        return p;
    };
    float* xf  = (float*)alloc((size_t)BL * H * 4);
    float* vbuf= (float*)alloc((size_t)BL * H * 4);
    float* y2  = (float*)alloc((size_t)BL * H * 4);
    unsigned short* xb  = (unsigned short*)alloc((size_t)BL * H * 2);
    unsigned short* y1b = (unsigned short*)alloc((size_t)BL * H * 2);
    unsigned short* WcB = (unsigned short*)alloc((size_t)2 * H * H * 2);
    unsigned short* W1B = (unsigned short*)alloc((size_t)2 * H * H * 2);
    unsigned short* W2B = (unsigned short*)alloc((size_t)2 * H * H * 2);
    unsigned short* embB= (unsigned short*)alloc((size_t)NPAD * H * 2);

    // --- prep ---
    k_f32_to_bf16<<<dim3(512), dim3(256), 0, stream>>>(W1, W1B, 2 * H * H);
    k_f32_to_bf16<<<dim3(512), dim3(256), 0, stream>>>(W2, W2B, 2 * H * H);
    k_wc<<<dim3(H, 2), dim3(H), 0, stream>>>(Wo, Wv, WcB);
    {
        int n4 = NPAD * H / 4;
        k_conv_emb<<<dim3((n4 + 255) / 256), dim3(256), 0, stream>>>(item_emb, embB);
    }

    // --- embedding + LN ---
    k_embed_ln<<<dim3(BL), dim3(H), 0, stream>>>(ids, item_emb, pos_emb, emb_g, emb_b, xf, xb);

    // --- transformer blocks ---
    for (int i = 0; i < 2; ++i) {
        // v = x @ Wc^T
        k_gemm64<0,0,1,0><<<dim3(BL / 64, H / 64), dim3(256), 0, stream>>>(
            xb, WcB + (size_t)i * H * H, nullptr, vbuf, nullptr, H, H);
        // mixed = cumsum(v)/counts (in place)
        k_cumsum<<<dim3(NB), dim3(H), 0, stream>>>(vbuf);
        // x = LN(x + mixed)*keep
        k_add_ln<<<dim3(BL), dim3(H), 0, stream>>>(
            xf, vbuf, attn_g + (size_t)i * H, attn_b + (size_t)i * H, ids, xf, xb);
        // y1 = relu(x @ W1^T + b1)  (bf16 only)
        k_gemm64<1,1,0,1><<<dim3(BL / 64, H / 64), dim3(256), 0, stream>>>(
            xb, W1B + (size_t)i * H * H, b1 + (size_t)i * H, nullptr, y1b, H, H);
        // y2 = y1 @ W2^T + b2
        k_gemm64<1,0,1,0><<<dim3(BL / 64, H / 64), dim3(256), 0, stream>>>(
            y1b, W2B + (size_t)i * H * H, b2 + (size_t)i * H, y2, nullptr, H, H);
        // x = LN(x + y2)*keep
        k_add_ln<<<dim3(BL), dim3(H), 0, stream>>>(
            xf, y2, ffn_g + (size_t)i * H, ffn_b + (size_t)i * H, ids, xf, xb);
    }

    // --- logits = x @ item_emb^T ---
    k_logits<<<dim3(LGWG), dim3(256), 0, stream>>>(xb, embB, out);
}